// Round 1
// baseline (3591.167 us; speedup 1.0000x reference)
//
#include <hip/hip_runtime.h>
#include <stdint.h>

// GRU: T=2048, B=128, I=256, H=256.
// Phase 1 (per chunk): gi = x @ w_ih^T + b_ih  -> bf16 in d_ws  (MFMA GEMM)
// Phase 2 (per chunk): serial scan, 128 WGs (one per batch row), w_hh held in
//   VGPRs as bf16 pairs, gh via v_dot2_f32_bf16. h state fp32 in registers,
//   broadcast per step through a tiny LDS buffer.

#define T_SEQ 2048
#define BATCH 128
#define IDIM  256
#define HDIM  256
#define G3    768   // 3*H

typedef float f32x4 __attribute__((ext_vector_type(4)));
typedef short bf16x8 __attribute__((ext_vector_type(8)));

__device__ __forceinline__ uint16_t f2bf(float f) {
  union { float f; uint32_t u; } v; v.f = f;
  uint32_t u = v.u;
  return (uint16_t)((u + 0x7fffu + ((u >> 16) & 1u)) >> 16);  // RNE
}
__device__ __forceinline__ uint32_t pack2(float a, float b) {
  return (uint32_t)f2bf(a) | ((uint32_t)f2bf(b) << 16);
}
__device__ __forceinline__ float bf2f(uint16_t h) {
  union { uint32_t u; float f; } v; v.u = ((uint32_t)h) << 16;
  return v.f;
}
__device__ __forceinline__ float dot2bf(uint32_t w, uint32_t h, float acc) {
#if defined(__has_builtin)
#if __has_builtin(__builtin_amdgcn_fdot2_f32_bf16)
  typedef __bf16 v2bf __attribute__((ext_vector_type(2)));
  union U { uint32_t u; v2bf v; };
  U a, b; a.u = w; b.u = h;
  return __builtin_amdgcn_fdot2_f32_bf16(a.v, b.v, acc, false);
#else
  asm("v_dot2_f32_bf16 %0, %1, %2, %0" : "+v"(acc) : "v"(w), "v"(h));
  return acc;
#endif
#else
  asm("v_dot2_f32_bf16 %0, %1, %2, %0" : "+v"(acc) : "v"(w), "v"(h));
  return acc;
#endif
}

// ---------------------------------------------------------------------------
// Phase 1: gi GEMM.  256 WGs x 512 thr (8 waves). Wave w owns N-slice
// [w*96, w*96+96) with w_ih frags persistent in VGPRs (192 dwords/thread).
// Each iteration: one M-tile of 16 rows, full N=768, K=256 (8 k-steps).
// Epilogue: acc(+bias) -> bf16 -> LDS -> coalesced dwordx4 stores.
// ---------------------------------------------------------------------------
#define GEMM_NT 6
#define GEMM_KS 8
#define LDSROW  1552  // padded row stride (bytes); 16B-aligned, breaks bank repeat

__global__ __launch_bounds__(512, 2)
void gi_gemm(const float* __restrict__ x, const float* __restrict__ w_ih,
             const float* __restrict__ b_ih, uint16_t* __restrict__ gi,
             int tiles) {
  __shared__ __align__(16) uint8_t lds_raw[16 * LDSROW];
  const int tid  = threadIdx.x;
  const int lane = tid & 63;
  const int wv   = tid >> 6;       // wave 0..7
  const int l15  = lane & 15;
  const int lk   = lane >> 4;      // 0..3

  // Preload B fragments (w_ih is [768][256] row-major = B^T, i.e. B[k][col]=w_ih[col][k])
  bf16x8 bfrag[GEMM_NT][GEMM_KS];
  float  bias[GEMM_NT];
#pragma unroll
  for (int nt = 0; nt < GEMM_NT; ++nt) {
    const int col = wv * 96 + nt * 16 + l15;
    bias[nt] = b_ih[col];
#pragma unroll
    for (int ks = 0; ks < GEMM_KS; ++ks) {
      const int kb = ks * 32 + lk * 8;
      const float4* p = (const float4*)(w_ih + (size_t)col * IDIM + kb);
      float4 w0 = p[0], w1 = p[1];
      union { uint32_t u[4]; bf16x8 v; } pk;
      pk.u[0] = pack2(w0.x, w0.y); pk.u[1] = pack2(w0.z, w0.w);
      pk.u[2] = pack2(w1.x, w1.y); pk.u[3] = pack2(w1.z, w1.w);
      bfrag[nt][ks] = pk.v;
    }
  }

  for (int tile = blockIdx.x; tile < tiles; tile += gridDim.x) {
    const int m0 = tile * 16;
    f32x4 acc[GEMM_NT];
#pragma unroll
    for (int nt = 0; nt < GEMM_NT; ++nt) {
      f32x4 z = {0.f, 0.f, 0.f, 0.f};
      acc[nt] = z;
    }
#pragma unroll
    for (int ks = 0; ks < GEMM_KS; ++ks) {
      const float4* p = (const float4*)(x + (size_t)(m0 + l15) * IDIM + ks * 32 + lk * 8);
      float4 a0 = p[0], a1 = p[1];
      union { uint32_t u[4]; bf16x8 v; } pk;
      pk.u[0] = pack2(a0.x, a0.y); pk.u[1] = pack2(a0.z, a0.w);
      pk.u[2] = pack2(a1.x, a1.y); pk.u[3] = pack2(a1.z, a1.w);
#pragma unroll
      for (int nt = 0; nt < GEMM_NT; ++nt)
        acc[nt] = __builtin_amdgcn_mfma_f32_16x16x32_bf16(pk.v, bfrag[nt][ks], acc[nt], 0, 0, 0);
    }
    // Epilogue: C/D layout col=lane&15, row=(lane>>4)*4+reg  [m89-verified]
#pragma unroll
    for (int nt = 0; nt < GEMM_NT; ++nt) {
      const int col = wv * 96 + nt * 16 + l15;
#pragma unroll
      for (int i = 0; i < 4; ++i) {
        const int row = lk * 4 + i;
        *(uint16_t*)(lds_raw + row * LDSROW + col * 2) = f2bf(acc[nt][i] + bias[nt]);
      }
    }
    __syncthreads();
    {
      const int row = tid >> 5, c = tid & 31;
      const uint4* src = (const uint4*)(lds_raw + row * LDSROW + c * 48);
      uint4* dst = (uint4*)((uint8_t*)gi + (size_t)(m0 + row) * G3 * 2 + c * 48);
      dst[0] = src[0]; dst[1] = src[1]; dst[2] = src[2];
    }
    __syncthreads();
  }
}

// ---------------------------------------------------------------------------
// Phase 2: serial scan. Grid = 128 (one WG per batch row), 512 threads:
// j = tid&255 (hidden unit), q = tid>>8 (k-half of 128). Thread holds
// w_hh[{r,z,n}*256+j][q*128..+127] as 3x64 packed bf16 pairs (192 VGPRs).
// Per step: 192 dot2 -> partials -> LDS reduce -> gates (q==0) -> h update.
// ---------------------------------------------------------------------------
__global__ __launch_bounds__(512, 2)
void gru_scan(const uint16_t* __restrict__ gi, const float* __restrict__ w_hh,
              const float* __restrict__ b_hh, const float* __restrict__ h0,
              float* __restrict__ hstate, float* __restrict__ out,
              int t0, int cT) {
  __shared__ __align__(16) uint4 hbuf4[32];   // 256 bf16 h values
  __shared__ float part[G3 * 2];              // [(g*256+j)*2 + q]
  const int b   = blockIdx.x;
  const int tid = threadIdx.x;
  const int j   = tid & 255;
  const int q   = tid >> 8;   // 0 or 1

  // Weight preload (once): 3 gates x 64 bf16-pairs
  uint32_t wr[64], wz[64], wn[64];
#pragma unroll
  for (int p = 0; p < 64; ++p) {
    float2 a = ((const float2*)(w_hh + (size_t)(0 * 256 + j) * HDIM + q * 128))[p];
    float2 c = ((const float2*)(w_hh + (size_t)(1 * 256 + j) * HDIM + q * 128))[p];
    float2 d = ((const float2*)(w_hh + (size_t)(2 * 256 + j) * HDIM + q * 128))[p];
    wr[p] = pack2(a.x, a.y);
    wz[p] = pack2(c.x, c.y);
    wn[p] = pack2(d.x, d.y);
  }
  const float bhr = b_hh[j], bhz = b_hh[256 + j], bhn = b_hh[512 + j];

  float h = 0.f;
  if (q == 0) {
    h = (t0 == 0) ? h0[b * HDIM + j] : hstate[b * HDIM + j];
    ((uint16_t*)hbuf4)[j] = f2bf(h);
  }
  __syncthreads();

  const uint16_t* gib = gi + (size_t)b * G3 + j;
  float gr = 0.f, gz = 0.f, gn = 0.f;
  if (q == 0) {
    const uint16_t* p = gib;
    gr = bf2f(p[0]); gz = bf2f(p[256]); gn = bf2f(p[512]);
  }

  for (int tt = 0; tt < cT; ++tt) {
    float ar = 0.f, az = 0.f, an = 0.f;
#pragma unroll
    for (int p16 = 0; p16 < 16; ++p16) {
      uint4 hv = hbuf4[q * 16 + p16];   // broadcast read (all lanes same addr)
      ar = dot2bf(wr[p16 * 4 + 0], hv.x, ar);
      az = dot2bf(wz[p16 * 4 + 0], hv.x, az);
      an = dot2bf(wn[p16 * 4 + 0], hv.x, an);
      ar = dot2bf(wr[p16 * 4 + 1], hv.y, ar);
      az = dot2bf(wz[p16 * 4 + 1], hv.y, az);
      an = dot2bf(wn[p16 * 4 + 1], hv.y, an);
      ar = dot2bf(wr[p16 * 4 + 2], hv.z, ar);
      az = dot2bf(wz[p16 * 4 + 2], hv.z, az);
      an = dot2bf(wn[p16 * 4 + 2], hv.z, an);
      ar = dot2bf(wr[p16 * 4 + 3], hv.w, ar);
      az = dot2bf(wz[p16 * 4 + 3], hv.w, az);
      an = dot2bf(wn[p16 * 4 + 3], hv.w, an);
    }
    part[(0 * 256 + j) * 2 + q] = ar;
    part[(1 * 256 + j) * 2 + q] = az;
    part[(2 * 256 + j) * 2 + q] = an;
    __syncthreads();
    if (q == 0) {
      float2 pr = *(const float2*)&part[(0 * 256 + j) * 2];
      float2 pz = *(const float2*)&part[(1 * 256 + j) * 2];
      float2 pn = *(const float2*)&part[(2 * 256 + j) * 2];
      float sr = gr + pr.x + pr.y + bhr;
      float sz = gz + pz.x + pz.y + bhz;
      float hn = pn.x + pn.y + bhn;           // gh_n + b_hh_n (b_hh_n inside r*())
      float r = 1.f / (1.f + __expf(-sr));
      float z = 1.f / (1.f + __expf(-sz));
      float xn = gn + r * hn;
      float e = __expf(-2.f * xn);
      float n = 1.f - 2.f * e / (1.f + e);    // tanh(xn)
      h = (1.f - z) * n + z * h;
      out[((size_t)(t0 + tt) * BATCH + b) * HDIM + j] = h;
      ((uint16_t*)hbuf4)[j] = f2bf(h);
      if (tt + 1 < cT) {
        const uint16_t* p = gib + (size_t)(tt + 1) * BATCH * G3;
        gr = bf2f(p[0]); gz = bf2f(p[256]); gn = bf2f(p[512]);
      }
    }
    __syncthreads();
  }

  if (q == 0) {
    hstate[b * HDIM + j] = h;
    if (t0 + cT == T_SEQ)
      out[(size_t)T_SEQ * BATCH * HDIM + (size_t)b * HDIM + j] = h;
  }
}

// ---------------------------------------------------------------------------
extern "C" void kernel_launch(void* const* d_in, const int* in_sizes, int n_in,
                              void* d_out, int out_size, void* d_ws, size_t ws_size,
                              hipStream_t stream) {
  const float* x    = (const float*)d_in[0];
  const float* h0   = (const float*)d_in[1];
  const float* w_ih = (const float*)d_in[2];
  const float* w_hh = (const float*)d_in[3];
  const float* b_ih = (const float*)d_in[4];
  const float* b_hh = (const float*)d_in[5];
  float* out = (float*)d_out;

  const size_t HST = 1 << 17;  // 128 KB reserved for fp32 h carry state
  float* hstate = (float*)d_ws;
  uint16_t* gi = (uint16_t*)((char*)d_ws + HST);

  const size_t per_t = (size_t)BATCH * G3 * 2;  // bytes of gi per timestep
  size_t cap = (ws_size > HST) ? (ws_size - HST) / per_t : 0;
  int chunk = (int)((cap < (size_t)T_SEQ) ? cap : (size_t)T_SEQ);
  if (chunk < 1) chunk = 1;

  for (int t0 = 0; t0 < T_SEQ; t0 += chunk) {
    const int cT = (T_SEQ - t0 < chunk) ? (T_SEQ - t0) : chunk;
    const int tiles = cT * BATCH / 16;
    gi_gemm<<<256, 512, 0, stream>>>(x + (size_t)t0 * BATCH * IDIM, w_ih, b_ih, gi, tiles);
    gru_scan<<<128, 512, 0, stream>>>(gi, w_hh, b_hh, h0, hstate, out, t0, cT);
  }
}